// Round 9
// baseline (864.065 us; speedup 1.0000x reference)
//
#include <hip/hip_runtime.h>
#include <hip/hip_bf16.h>

#define N_NODES   100000
#define N_EDGES   1600000
#define CH        128
#define N_GRAPHS  512
#define N_CLASSES 64
#define BN_EPS    1e-5f
#define N_PAD     100128   /* N_NODES rounded up past 128-row gemm tile */

// Node features in channel-blocked layout: [cb][node][16ch], cb in 0..7.
// Slice = N_PAD*16*2 B = 3.2 MB -> fits one XCD's 4 MB L2.
#define SLICE ((size_t)N_PAD * 16)

typedef unsigned int uint;
typedef unsigned short ushort_t;

typedef short bf16x8 __attribute__((ext_vector_type(8)));
typedef float f32x4  __attribute__((ext_vector_type(4)));
typedef float f32x2  __attribute__((ext_vector_type(2)));

__device__ __forceinline__ ushort_t f2bf(float f) {
    uint u = __float_as_uint(f);
    uint r = (u + 0x7fffu + ((u >> 16) & 1u)) >> 16;   // round-to-nearest-even
    return (ushort_t)r;
}
__device__ __forceinline__ float bf2f(ushort_t u) {
    return __uint_as_float(((uint)u) << 16);
}
// low bf16 -> .x, high bf16 -> .y (as floats); enables v_pk_add_f32
__device__ __forceinline__ f32x2 bfpair(uint u) {
    f32x2 r;
    r.x = __uint_as_float(u << 16);
    r.y = __uint_as_float(u & 0xffff0000u);
    return r;
}

// ---------------- degree count + per-edge rank ----------------
__global__ __launch_bounds__(256) void k_deg(const int* __restrict__ dst,
                                             int* __restrict__ cnt,
                                             int* __restrict__ rank) {
    int e = blockIdx.x * 256 + threadIdx.x;
    if (e < N_EDGES) rank[e] = atomicAdd(&cnt[dst[e]], 1);
}

// ---------------- exclusive scan (3-kernel, 100K elems) ----------------
__global__ __launch_bounds__(512) void k_scan1(const int* __restrict__ cnt,
                                               int* __restrict__ lofs,
                                               int* __restrict__ bsum) {
    __shared__ int sd[512];
    int t = threadIdx.x;
    int i = blockIdx.x * 512 + t;
    int v = (i < N_NODES) ? cnt[i] : 0;
    sd[t] = v;
    __syncthreads();
    for (int o = 1; o < 512; o <<= 1) {
        int x = (t >= o) ? sd[t - o] : 0;
        __syncthreads();
        sd[t] += x;
        __syncthreads();
    }
    if (i < N_NODES) lofs[i] = sd[t] - v;     // exclusive
    if (t == 511) bsum[blockIdx.x] = sd[511];
}

__global__ __launch_bounds__(256) void k_scan2(int* __restrict__ bsum, int nblocks) {
    __shared__ int sd[256];
    int t = threadIdx.x;
    int v = (t < nblocks) ? bsum[t] : 0;
    sd[t] = v;
    __syncthreads();
    for (int o = 1; o < 256; o <<= 1) {
        int x = (t >= o) ? sd[t - o] : 0;
        __syncthreads();
        sd[t] += x;
        __syncthreads();
    }
    if (t < nblocks) bsum[t] = sd[t] - v;     // exclusive
}

__global__ __launch_bounds__(256) void k_scan3(const int* __restrict__ lofs,
                                               const int* __restrict__ bsum,
                                               const int* __restrict__ cnt,
                                               int* __restrict__ offs,
                                               float* __restrict__ dinv) {
    int i = blockIdx.x * 256 + threadIdx.x;
    if (i < N_NODES) {
        offs[i] = lofs[i] + bsum[i >> 9];
        dinv[i] = rsqrtf((float)cnt[i] + 1.0f);
    }
    if (i == 0) offs[N_NODES] = N_EDGES;
}

// ---------------- CSR fill (no atomics: rank precomputed) ----------------
__global__ __launch_bounds__(256) void k_fill(const int* __restrict__ src,
                                              const int* __restrict__ dst,
                                              const int* __restrict__ offs,
                                              const int* __restrict__ rank,
                                              int* __restrict__ csr_src) {
    int e = blockIdx.x * 256 + threadIdx.x;
    if (e >= N_EDGES) return;
    int pos = offs[dst[e]] + rank[e];
    csr_src[pos] = src[e];
}

// ---------------- fused weight transpose + x cast (blocked layout out) ----------------
#define PREP_BLOCKS 192
__global__ __launch_bounds__(256) void k_precast(const float* __restrict__ W1,
                                                 const float* __restrict__ W2,
                                                 const float* __restrict__ W3,
                                                 ushort_t* __restrict__ Wt,
                                                 const float* __restrict__ x,
                                                 ushort_t* __restrict__ XB) {
    if (blockIdx.x < PREP_BLOCKS) {
        int tid = blockIdx.x * 256 + threadIdx.x;      // < 3*16384
        int l = tid >> 14;
        int e = tid & 16383;
        int n = e >> 7;
        int k = e & 127;
        const float* W = (l == 0) ? W1 : (l == 1) ? W2 : W3;
        Wt[l * 16384 + n * 128 + k] = f2bf(W[k * 128 + n]);
    } else {
        int tid = (blockIdx.x - PREP_BLOCKS) * 256 + threadIdx.x;
        if (tid >= N_NODES * 32) return;
        int i = tid >> 5;
        int cg = tid & 31;
        int c = cg * 4;
        float4 v = *(const float4*)&x[(size_t)i * 128 + c];
        ushort4 o;
        o.x = f2bf(v.x); o.y = f2bf(v.y); o.z = f2bf(v.z); o.w = f2bf(v.w);
        *(ushort4*)&XB[(size_t)(cg >> 2) * SLICE + (size_t)i * 16 + (c & 15)] = o;
    }
}

// ---------------- MFMA GEMM: Hs(bf16, blocked) = dinv * (XB(bf16, blocked) @ W) ----------------
__global__ __launch_bounds__(256) void k_gemm(const ushort_t* __restrict__ XB,
                                              const ushort_t* __restrict__ Wt,
                                              const float* __restrict__ dinv,
                                              ushort_t* __restrict__ H) {
    const int t = threadIdx.x;
    const int wave = t >> 6;
    const int lane = t & 63;
    const int q = lane >> 4;       // quad 0..3
    const int r = lane & 15;
    const int row0 = blockIdx.x * 128 + (wave >> 1) * 64;
    const int col0 = (wave & 1) * 64;
    const int cb0 = (wave & 1) * 4;

    f32x4 acc[4][4];
#pragma unroll
    for (int i = 0; i < 4; ++i)
#pragma unroll
        for (int j = 0; j < 4; ++j)
            acc[i][j] = (f32x4){0.f, 0.f, 0.f, 0.f};

#pragma unroll
    for (int ks = 0; ks < 4; ++ks) {
        const int k0 = ks * 32 + q * 8;
        const size_t abase = (size_t)(k0 >> 4) * SLICE + (k0 & 15);
        bf16x8 a[4], b[4];
#pragma unroll
        for (int i = 0; i < 4; ++i)
            a[i] = *(const bf16x8*)(XB + abase + (size_t)(row0 + i * 16 + r) * 16);
#pragma unroll
        for (int j = 0; j < 4; ++j)
            b[j] = *(const bf16x8*)(Wt + (size_t)(col0 + j * 16 + r) * 128 + k0);
#pragma unroll
        for (int i = 0; i < 4; ++i)
#pragma unroll
            for (int j = 0; j < 4; ++j)
                acc[i][j] = __builtin_amdgcn_mfma_f32_16x16x32_bf16(a[i], b[j], acc[i][j], 0, 0, 0);
    }

#pragma unroll
    for (int i = 0; i < 4; ++i) {
#pragma unroll
        for (int rg = 0; rg < 4; ++rg) {
            int rr = row0 + i * 16 + q * 4 + rg;
            if (rr < N_NODES) {
                float dv = dinv[rr];
#pragma unroll
                for (int j = 0; j < 4; ++j)
                    H[(size_t)(cb0 + j) * SLICE + (size_t)rr * 16 + r] = f2bf(acc[i][j][rg] * dv);
            }
        }
    }
}

// ---------------- gather-aggregate v4: 4-lane group per node, blocked + XCD-affine ----------------
// cb = blockIdx&7 (round-robin -> XCD keeps the 3.2 MB H slice L2-resident).
// Each 4-lane group owns one node: loops its edge list, 32 B row per edge
// (uint2/lane), register accumulation — no shuffles, no cross-node reduction.
__global__ __launch_bounds__(256) void k_gather(const int* __restrict__ csr_src,
                                                const int* __restrict__ offs,
                                                const float* __restrict__ dinv,
                                                const ushort_t* __restrict__ H,
                                                const float* __restrict__ b,
                                                ushort_t* __restrict__ AGG) {
    const int cb = blockIdx.x & 7;
    const int node = (blockIdx.x >> 3) * 64 + (threadIdx.x >> 2);
    if (node >= N_NODES) return;
    const int k4 = (threadIdx.x & 3) * 4;
    const ushort_t* __restrict__ Hb = H + (size_t)cb * SLICE;

    uint2 hv = *(const uint2*)(Hb + (size_t)node * 16 + k4);   // self (dinv-scaled)
    f32x2 a01 = bfpair(hv.x);
    f32x2 a23 = bfpair(hv.y);

    int p = __builtin_nontemporal_load(offs + node);
    int end = __builtin_nontemporal_load(offs + node + 1);

    for (; p + 4 <= end; p += 4) {
        int s0 = __builtin_nontemporal_load(csr_src + p);
        int s1 = __builtin_nontemporal_load(csr_src + p + 1);
        int s2 = __builtin_nontemporal_load(csr_src + p + 2);
        int s3 = __builtin_nontemporal_load(csr_src + p + 3);
        uint2 h0 = *(const uint2*)(Hb + (size_t)s0 * 16 + k4);
        uint2 h1 = *(const uint2*)(Hb + (size_t)s1 * 16 + k4);
        uint2 h2 = *(const uint2*)(Hb + (size_t)s2 * 16 + k4);
        uint2 h3 = *(const uint2*)(Hb + (size_t)s3 * 16 + k4);
        a01 += bfpair(h0.x); a23 += bfpair(h0.y);
        a01 += bfpair(h1.x); a23 += bfpair(h1.y);
        a01 += bfpair(h2.x); a23 += bfpair(h2.y);
        a01 += bfpair(h3.x); a23 += bfpair(h3.y);
    }
    for (; p < end; ++p) {
        int s = __builtin_nontemporal_load(csr_src + p);
        uint2 h = *(const uint2*)(Hb + (size_t)s * 16 + k4);
        a01 += bfpair(h.x); a23 += bfpair(h.y);
    }

    float di = dinv[node];
    float4 bias = *(const float4*)&b[cb * 16 + k4];
    float r0 = a01.x * di + bias.x;
    float r1 = a01.y * di + bias.y;
    float r2 = a23.x * di + bias.z;
    float r3 = a23.y * di + bias.w;
    uint2 o;
    o.x = (uint)f2bf(r0) | ((uint)f2bf(r1) << 16);
    o.y = (uint)f2bf(r2) | ((uint)f2bf(r3) << 16);
    *(uint2*)(AGG + (size_t)cb * SLICE + (size_t)node * 16 + k4) = o;
}

// ---------------- BN stats: per-channel sum / sumsq (blocked, coalesced) ----------------
__global__ __launch_bounds__(128) void k_bn_stats(const ushort_t* __restrict__ AGG,
                                                  float* __restrict__ stats) {
    __shared__ float ss[128], qq[128];
    int t = threadIdx.x;
    int ii = t >> 4;               // 0..7
    int k = t & 15;
    int cb = blockIdx.x & 7;
    int chunk = blockIdx.x >> 3;   // 0..127
    const ushort_t* base = AGG + (size_t)cb * SLICE;
    float s = 0.f, q = 0.f;
    for (int i = chunk * 8 + ii; i < N_NODES; i += 1024) {
        float v = bf2f(base[(size_t)i * 16 + k]);
        s += v; q += v * v;
    }
    ss[t] = s; qq[t] = q;
    __syncthreads();
    if (ii < 4) { ss[t] += ss[t + 64]; qq[t] += qq[t + 64]; }
    __syncthreads();
    if (ii < 2) { ss[t] += ss[t + 32]; qq[t] += qq[t + 32]; }
    __syncthreads();
    if (ii == 0) {
        atomicAdd(&stats[cb * 16 + k], ss[t] + ss[t + 16]);
        atomicAdd(&stats[128 + cb * 16 + k], qq[t] + qq[t + 16]);
    }
}

// ---------------- BN apply (finalize fused) + ReLU (+ residual), blocked bf16 ----------------
__global__ __launch_bounds__(256) void k_bn_apply(const ushort_t* __restrict__ AGG,
                                                  const float* __restrict__ stats,
                                                  const float* __restrict__ gamma,
                                                  const float* __restrict__ beta,
                                                  const ushort_t* __restrict__ RES,  // may be null
                                                  ushort_t* __restrict__ OUT) {
    int tid = blockIdx.x * 256 + threadIdx.x;      // covers 8*N_PAD*4 quads
    if (tid >= N_PAD * 32) return;
    int cb = tid / (N_PAD * 4);
    int c = cb * 16 + (tid & 3) * 4;               // logical channel of this quad
    size_t idx = (size_t)tid * 4;                  // flat blocked address

    const float invN = 1.0f / (float)N_NODES;
    float4 sm = *(const float4*)&stats[c];
    float4 sq = *(const float4*)&stats[128 + c];
    float4 gm = *(const float4*)&gamma[c];
    float4 bt = *(const float4*)&beta[c];
    float mu0 = sm.x * invN, mu1 = sm.y * invN, mu2 = sm.z * invN, mu3 = sm.w * invN;
    float sc0 = gm.x * rsqrtf(sq.x * invN - mu0 * mu0 + BN_EPS);
    float sc1 = gm.y * rsqrtf(sq.y * invN - mu1 * mu1 + BN_EPS);
    float sc2 = gm.z * rsqrtf(sq.z * invN - mu2 * mu2 + BN_EPS);
    float sc3 = gm.w * rsqrtf(sq.w * invN - mu3 * mu3 + BN_EPS);
    float sh0 = bt.x - mu0 * sc0, sh1 = bt.y - mu1 * sc1;
    float sh2 = bt.z - mu2 * sc2, sh3 = bt.w - mu3 * sc3;

    uint2 av = *(const uint2*)&AGG[idx];
    float y0 = bf2f((ushort_t)(av.x & 0xffff)) * sc0 + sh0;
    float y1 = bf2f((ushort_t)(av.x >> 16))    * sc1 + sh1;
    float y2 = bf2f((ushort_t)(av.y & 0xffff)) * sc2 + sh2;
    float y3 = bf2f((ushort_t)(av.y >> 16))    * sc3 + sh3;
    if (RES) {
        ushort4 rv = *(const ushort4*)&RES[idx];
        y0 += bf2f(rv.x); y1 += bf2f(rv.y); y2 += bf2f(rv.z); y3 += bf2f(rv.w);
    }
    ushort4 o;
    o.x = f2bf(fmaxf(y0, 0.f)); o.y = f2bf(fmaxf(y1, 0.f));
    o.z = f2bf(fmaxf(y2, 0.f)); o.w = f2bf(fmaxf(y3, 0.f));
    *(ushort4*)&OUT[idx] = o;
}

// ---------------- layer-3 fused BN + ReLU + residual + pool (blocked in, out3 never stored) --------
#define POOL_CHUNK 100
__global__ __launch_bounds__(128) void k_bn_pool(const ushort_t* __restrict__ AGG,
                                                 const float* __restrict__ stats,
                                                 const float* __restrict__ gamma,
                                                 const float* __restrict__ beta,
                                                 const ushort_t* __restrict__ RES,
                                                 const int* __restrict__ batch,
                                                 float* __restrict__ psum,
                                                 uint* __restrict__ pmax,
                                                 float* __restrict__ pcnt) {
    int t = threadIdx.x;                        // logical channel (= cb*16 + k)
    const ushort_t* abase = AGG + (size_t)(t >> 4) * SLICE + (t & 15);
    const ushort_t* rbase = RES + (size_t)(t >> 4) * SLICE + (t & 15);
    const float invN = 1.0f / (float)N_NODES;
    float mu = stats[t] * invN;
    float sc = gamma[t] * rsqrtf(stats[128 + t] * invN - mu * mu + BN_EPS);
    float sh = beta[t] - mu * sc;

    int i0 = blockIdx.x * POOL_CHUNK;
    int i1 = min(i0 + POOL_CHUNK, N_NODES);
    if (i0 >= i1) return;

    int cur = batch[i0];
    float s = 0.f, m = 0.f, cntf = 0.f;
    for (int i = i0; i < i1; ++i) {
        int b = batch[i];
        float v = bf2f(abase[(size_t)i * 16]) * sc + sh + bf2f(rbase[(size_t)i * 16]);
        v = fmaxf(v, 0.f);
        if (b != cur) {
            atomicAdd(&psum[cur * 128 + t], s);
            atomicMax(&pmax[cur * 128 + t], __float_as_uint(m));
            if (t == 0) atomicAdd(&pcnt[cur], cntf);
            s = 0.f; m = 0.f; cntf = 0.f;
            cur = b;
        }
        s += v;
        m = fmaxf(m, v);   // post-ReLU >= 0: uint atomicMax == float max, init 0
        cntf += 1.f;
    }
    atomicAdd(&psum[cur * 128 + t], s);
    atomicMax(&pmax[cur * 128 + t], __float_as_uint(m));
    if (t == 0) atomicAdd(&pcnt[cur], cntf);
}

// ---------------- head ----------------
__global__ __launch_bounds__(64) void k_head(const float* __restrict__ psum,
                                             const uint* __restrict__ pmax,
                                             const float* __restrict__ pcnt,
                                             const float* __restrict__ Wh,
                                             const float* __restrict__ bh,
                                             float* __restrict__ out) {
    int g = blockIdx.x;
    int o = threadIdx.x;
    float cnt = pcnt[g];
    float inv = 1.0f / fmaxf(cnt, 1.0f);
    float acc = bh[o];
    for (int c = 0; c < 128; ++c) {
        float s = psum[g * 128 + c];
        float m = __uint_as_float(pmax[g * 128 + c]);
        acc += (s * inv) * Wh[c * 64 + o];
        acc += s * Wh[(128 + c) * 64 + o];
        acc += m * Wh[(256 + c) * 64 + o];
    }
    out[g * 64 + o] = acc;
}

// ---------------- host orchestration ----------------
extern "C" void kernel_launch(void* const* d_in, const int* in_sizes, int n_in,
                              void* d_out, int out_size, void* d_ws, size_t ws_size,
                              hipStream_t stream) {
    const float* x     = (const float*)d_in[0];
    const int*   ei    = (const int*)d_in[1];
    const int*   batch = (const int*)d_in[2];
    const float* W1 = (const float*)d_in[3];
    const float* b1 = (const float*)d_in[4];
    const float* g1 = (const float*)d_in[5];
    const float* be1= (const float*)d_in[6];
    const float* W2 = (const float*)d_in[7];
    const float* b2 = (const float*)d_in[8];
    const float* g2 = (const float*)d_in[9];
    const float* be2= (const float*)d_in[10];
    const float* W3 = (const float*)d_in[11];
    const float* b3 = (const float*)d_in[12];
    const float* g3 = (const float*)d_in[13];
    const float* be3= (const float*)d_in[14];
    const float* Wh = (const float*)d_in[15];
    const float* bh = (const float*)d_in[16];

    const int* src = ei;
    const int* dst = ei + N_EDGES;

    char* ws = (char*)d_ws;
    size_t off = 0;

    // ---- zero-initialized contiguous region (single memset) ----
    char* zero_base = ws;
    int*   cnt     = (int*)(ws + off);      off += 400384;                       // N_NODES*4 padded
    float* stats   = (float*)(ws + off);    off += 3 * 512 * 4;                  // 3 layers x 512 floats
    float* psum    = (float*)(ws + off);    off += (size_t)N_GRAPHS * CH * 4;
    uint*  pmax    = (uint*)(ws + off);     off += (size_t)N_GRAPHS * CH * 4;
    float* pcnt    = (float*)(ws + off);    off += 4096;
    size_t zero_bytes = off;

    // ---- uninitialized scratch ----
    float* dinv    = (float*)(ws + off);    off += 512 * 1024;
    ushort_t* XBA  = (ushort_t*)(ws + off); off += (size_t)N_PAD * CH * 2;
    ushort_t* XBB  = (ushort_t*)(ws + off); off += (size_t)N_PAD * CH * 2;
    ushort_t* H    = (ushort_t*)(ws + off); off += (size_t)N_PAD * CH * 2;
    ushort_t* AGG  = (ushort_t*)(ws + off); off += (size_t)N_PAD * CH * 2;
    ushort_t* Wt   = (ushort_t*)(ws + off); off += 3 * 16384 * 2;
    int*   lofs    = (int*)(ws + off);      off += 512 * 1024;
    int*   offs    = (int*)(ws + off);      off += 512 * 1024;      // N+1 ints
    int*   bsum    = (int*)(ws + off);      off += 4096;
    int*   rank    = (int*)(ws + off);      off += (size_t)N_EDGES * 4;
    int*   csr_src = (int*)(ws + off);      off += (size_t)N_EDGES * 4;

    const int SCAN_BLOCKS = (N_NODES + 511) / 512;   // 196

    hipMemsetAsync(zero_base, 0, zero_bytes, stream);

    // weight transpose + x cast (blocked), then degree/rank
    const int cast_blocks = (N_NODES * 32 + 255) / 256;
    k_precast<<<PREP_BLOCKS + cast_blocks, 256, 0, stream>>>(W1, W2, W3, Wt, x, XBA);
    k_deg<<<(N_EDGES + 255) / 256, 256, 0, stream>>>(dst, cnt, rank);

    // scan(+dinv) / CSR fill
    k_scan1<<<SCAN_BLOCKS, 512, 0, stream>>>(cnt, lofs, bsum);
    k_scan2<<<1, 256, 0, stream>>>(bsum, SCAN_BLOCKS);
    k_scan3<<<(N_NODES + 255) / 256, 256, 0, stream>>>(lofs, bsum, cnt, offs, dinv);
    k_fill<<<(N_EDGES + 255) / 256, 256, 0, stream>>>(src, dst, offs, rank, csr_src);

    const int gemm_grid   = (N_NODES + 127) / 128;        // 782
    const int gather_grid = 8 * ((N_NODES + 63) / 64);    // 12504
    const int apply_grid  = (N_PAD * 32 + 255) / 256;
    const int pool_grid   = (N_NODES + POOL_CHUNK - 1) / POOL_CHUNK;

    struct Layer { const ushort_t* in; ushort_t* out; const ushort_t* Wt; const float* b;
                   const float* gm; const float* bt; const ushort_t* res; };
    Layer layers[3] = {
        { XBA, XBB, Wt,             b1, g1, be1, nullptr },
        { XBB, XBA, Wt + 16384,     b2, g2, be2, XBB     },
        { XBA, XBB, Wt + 2 * 16384, b3, g3, be3, XBA     },
    };

    for (int l = 0; l < 3; ++l) {
        const Layer& L = layers[l];
        float* st = stats + l * 512;
        k_gemm<<<gemm_grid, 256, 0, stream>>>(L.in, L.Wt, dinv, H);
        k_gather<<<gather_grid, 256, 0, stream>>>(csr_src, offs, dinv, H, L.b, AGG);
        k_bn_stats<<<1024, 128, 0, stream>>>(AGG, st);
        if (l < 2) {
            k_bn_apply<<<apply_grid, 256, 0, stream>>>(AGG, st, L.gm, L.bt, L.res, L.out);
        } else {
            k_bn_pool<<<pool_grid, 128, 0, stream>>>(AGG, st, L.gm, L.bt, L.res,
                                                     batch, psum, pmax, pcnt);
        }
    }

    k_head<<<N_GRAPHS, 64, 0, stream>>>(psum, pmax, pcnt, Wh, bh, (float*)d_out);
}

// Round 11
// 758.604 us; speedup vs baseline: 1.1390x; 1.1390x over previous
//
#include <hip/hip_runtime.h>
#include <hip/hip_bf16.h>

#define N_NODES   100000
#define N_EDGES   1600000
#define CH        128
#define N_GRAPHS  512
#define N_CLASSES 64
#define BN_EPS    1e-5f
#define N_PAD     100128   /* N_NODES rounded up past 128-row gemm tile */

typedef unsigned int uint;
typedef unsigned short ushort_t;

typedef short bf16x8 __attribute__((ext_vector_type(8)));
typedef float f32x4  __attribute__((ext_vector_type(4)));
typedef float f32x2  __attribute__((ext_vector_type(2)));

__device__ __forceinline__ ushort_t f2bf(float f) {
    uint u = __float_as_uint(f);
    uint r = (u + 0x7fffu + ((u >> 16) & 1u)) >> 16;   // round-to-nearest-even
    return (ushort_t)r;
}
__device__ __forceinline__ float bf2f(ushort_t u) {
    return __uint_as_float(((uint)u) << 16);
}
// low bf16 -> .x, high bf16 -> .y (as floats); enables v_pk_add_f32
__device__ __forceinline__ f32x2 bfpair(uint u) {
    f32x2 r;
    r.x = __uint_as_float(u << 16);
    r.y = __uint_as_float(u & 0xffff0000u);
    return r;
}

// ---------------- degree count + per-edge rank ----------------
__global__ __launch_bounds__(256) void k_deg(const int* __restrict__ dst,
                                             int* __restrict__ cnt,
                                             int* __restrict__ rank) {
    int e = blockIdx.x * 256 + threadIdx.x;
    if (e < N_EDGES) rank[e] = atomicAdd(&cnt[dst[e]], 1);
}

// ---------------- exclusive scan (3-kernel, 100K elems) ----------------
__global__ __launch_bounds__(512) void k_scan1(const int* __restrict__ cnt,
                                               int* __restrict__ lofs,
                                               int* __restrict__ bsum) {
    __shared__ int sd[512];
    int t = threadIdx.x;
    int i = blockIdx.x * 512 + t;
    int v = (i < N_NODES) ? cnt[i] : 0;
    sd[t] = v;
    __syncthreads();
    for (int o = 1; o < 512; o <<= 1) {
        int x = (t >= o) ? sd[t - o] : 0;
        __syncthreads();
        sd[t] += x;
        __syncthreads();
    }
    if (i < N_NODES) lofs[i] = sd[t] - v;     // exclusive
    if (t == 511) bsum[blockIdx.x] = sd[511];
}

__global__ __launch_bounds__(256) void k_scan2(int* __restrict__ bsum, int nblocks) {
    __shared__ int sd[256];
    int t = threadIdx.x;
    int v = (t < nblocks) ? bsum[t] : 0;
    sd[t] = v;
    __syncthreads();
    for (int o = 1; o < 256; o <<= 1) {
        int x = (t >= o) ? sd[t - o] : 0;
        __syncthreads();
        sd[t] += x;
        __syncthreads();
    }
    if (t < nblocks) bsum[t] = sd[t] - v;     // exclusive
}

__global__ __launch_bounds__(256) void k_scan3(const int* __restrict__ lofs,
                                               const int* __restrict__ bsum,
                                               const int* __restrict__ cnt,
                                               int* __restrict__ offs,
                                               float* __restrict__ dinv) {
    int i = blockIdx.x * 256 + threadIdx.x;
    if (i < N_NODES) {
        offs[i] = lofs[i] + bsum[i >> 9];
        dinv[i] = rsqrtf((float)cnt[i] + 1.0f);
    }
    if (i == 0) offs[N_NODES] = N_EDGES;
}

// ---------------- CSR fill (no atomics: rank precomputed) ----------------
__global__ __launch_bounds__(256) void k_fill(const int* __restrict__ src,
                                              const int* __restrict__ dst,
                                              const int* __restrict__ offs,
                                              const int* __restrict__ rank,
                                              int* __restrict__ csr_src) {
    int e = blockIdx.x * 256 + threadIdx.x;
    if (e >= N_EDGES) return;
    int pos = offs[dst[e]] + rank[e];
    csr_src[pos] = src[e];
}

// ---------------- fused weight transpose + x cast ----------------
#define PREP_BLOCKS 192
__global__ __launch_bounds__(256) void k_precast(const float* __restrict__ W1,
                                                 const float* __restrict__ W2,
                                                 const float* __restrict__ W3,
                                                 ushort_t* __restrict__ Wt,
                                                 const float* __restrict__ x,
                                                 ushort_t* __restrict__ XB) {
    if (blockIdx.x < PREP_BLOCKS) {
        int tid = blockIdx.x * 256 + threadIdx.x;      // < 3*16384
        int l = tid >> 14;
        int e = tid & 16383;
        int n = e >> 7;
        int k = e & 127;
        const float* W = (l == 0) ? W1 : (l == 1) ? W2 : W3;
        Wt[l * 16384 + n * 128 + k] = f2bf(W[k * 128 + n]);
    } else {
        int tid = (blockIdx.x - PREP_BLOCKS) * 256 + threadIdx.x;
        if (tid >= N_NODES * 32) return;
        int i = tid >> 5;
        int c = (tid & 31) * 4;
        float4 v = *(const float4*)&x[(size_t)i * 128 + c];
        ushort4 o;
        o.x = f2bf(v.x); o.y = f2bf(v.y); o.z = f2bf(v.z); o.w = f2bf(v.w);
        *(ushort4*)&XB[(size_t)i * 128 + c] = o;
    }
}

// ---------------- MFMA GEMM: Hs(bf16) = dinv * (XB(bf16) @ W) ----------------
__global__ __launch_bounds__(256) void k_gemm(const ushort_t* __restrict__ XB,
                                              const ushort_t* __restrict__ Wt,
                                              const float* __restrict__ dinv,
                                              ushort_t* __restrict__ H) {
    const int t = threadIdx.x;
    const int wave = t >> 6;
    const int lane = t & 63;
    const int q = lane >> 4;       // quad 0..3
    const int r = lane & 15;
    const int row0 = blockIdx.x * 128 + (wave >> 1) * 64;
    const int col0 = (wave & 1) * 64;

    f32x4 acc[4][4];
#pragma unroll
    for (int i = 0; i < 4; ++i)
#pragma unroll
        for (int j = 0; j < 4; ++j)
            acc[i][j] = (f32x4){0.f, 0.f, 0.f, 0.f};

#pragma unroll
    for (int ks = 0; ks < 4; ++ks) {
        const int k0 = ks * 32 + q * 8;
        bf16x8 a[4], b[4];
#pragma unroll
        for (int i = 0; i < 4; ++i)
            a[i] = *(const bf16x8*)(XB + (size_t)(row0 + i * 16 + r) * 128 + k0);
#pragma unroll
        for (int j = 0; j < 4; ++j)
            b[j] = *(const bf16x8*)(Wt + (size_t)(col0 + j * 16 + r) * 128 + k0);
#pragma unroll
        for (int i = 0; i < 4; ++i)
#pragma unroll
            for (int j = 0; j < 4; ++j)
                acc[i][j] = __builtin_amdgcn_mfma_f32_16x16x32_bf16(a[i], b[j], acc[i][j], 0, 0, 0);
    }

#pragma unroll
    for (int i = 0; i < 4; ++i) {
#pragma unroll
        for (int rg = 0; rg < 4; ++rg) {
            int rr = row0 + i * 16 + q * 4 + rg;
            if (rr < N_NODES) {
                float dv = dinv[rr];
#pragma unroll
                for (int j = 0; j < 4; ++j)
                    H[(size_t)rr * 128 + col0 + j * 16 + r] = f2bf(acc[i][j][rg] * dv);
            }
        }
    }
}

// ---------------- gather-aggregate: one wave per dst node, 2 edges per pass ----------------
// lanes 0..31 = edge A (4 ch each via uint2), lanes 32..63 = edge B; butterfly combine.
// AGG (bf16) = dinv[i]*(sum_nbr Hs + Hs[i]) + b
__global__ __launch_bounds__(256) void k_gather(const int* __restrict__ csr_src,
                                                const int* __restrict__ offs,
                                                const float* __restrict__ dinv,
                                                const ushort_t* __restrict__ H,
                                                const float* __restrict__ b,
                                                ushort_t* __restrict__ AGG) {
    int node = blockIdx.x * 4 + (threadIdx.x >> 6);
    if (node >= N_NODES) return;
    int lane = threadIdx.x & 63;
    int pair = lane >> 5;          // which edge of the dual
    int cl = lane & 31;
    int c = cl * 4;                // 4 channels per lane

    f32x2 a01 = (f32x2){0.f, 0.f};
    f32x2 a23 = (f32x2){0.f, 0.f};
    if (pair == 0) {               // self term (dinv-scaled H row)
        uint2 hv = *(const uint2*)(H + (size_t)node * 128 + c);
        a01 = bfpair(hv.x);
        a23 = bfpair(hv.y);
    }

    int p = __builtin_nontemporal_load(offs + node);
    int end = __builtin_nontemporal_load(offs + node + 1);

#define ACCUM(hv)  do { a01 += bfpair((hv).x); a23 += bfpair((hv).y); } while (0)

    for (; p + 16 <= end; p += 16) {          // 16 edges: 8 dual-loads in flight
        int s0 = __builtin_nontemporal_load(csr_src + p      + pair);
        int s1 = __builtin_nontemporal_load(csr_src + p +  2 + pair);
        int s2 = __builtin_nontemporal_load(csr_src + p +  4 + pair);
        int s3 = __builtin_nontemporal_load(csr_src + p +  6 + pair);
        int s4 = __builtin_nontemporal_load(csr_src + p +  8 + pair);
        int s5 = __builtin_nontemporal_load(csr_src + p + 10 + pair);
        int s6 = __builtin_nontemporal_load(csr_src + p + 12 + pair);
        int s7 = __builtin_nontemporal_load(csr_src + p + 14 + pair);
        uint2 h0 = *(const uint2*)(H + (size_t)s0 * 128 + c);
        uint2 h1 = *(const uint2*)(H + (size_t)s1 * 128 + c);
        uint2 h2 = *(const uint2*)(H + (size_t)s2 * 128 + c);
        uint2 h3 = *(const uint2*)(H + (size_t)s3 * 128 + c);
        uint2 h4 = *(const uint2*)(H + (size_t)s4 * 128 + c);
        uint2 h5 = *(const uint2*)(H + (size_t)s5 * 128 + c);
        uint2 h6 = *(const uint2*)(H + (size_t)s6 * 128 + c);
        uint2 h7 = *(const uint2*)(H + (size_t)s7 * 128 + c);
        ACCUM(h0); ACCUM(h1); ACCUM(h2); ACCUM(h3);
        ACCUM(h4); ACCUM(h5); ACCUM(h6); ACCUM(h7);
    }
    for (; p + 4 <= end; p += 4) {            // 4 edges: 2 dual-loads
        int s0 = __builtin_nontemporal_load(csr_src + p + pair);
        int s1 = __builtin_nontemporal_load(csr_src + p + 2 + pair);
        uint2 h0 = *(const uint2*)(H + (size_t)s0 * 128 + c);
        uint2 h1 = *(const uint2*)(H + (size_t)s1 * 128 + c);
        ACCUM(h0); ACCUM(h1);
    }
    for (; p < end; p += 2) {                 // tail: 1-2 edges, predicated
        int idx = p + pair;
        bool ok = idx < end;
        int s = __builtin_nontemporal_load(csr_src + (ok ? idx : p));
        uint2 h = *(const uint2*)(H + (size_t)s * 128 + c);
        if (ok) ACCUM(h);
    }
#undef ACCUM

    a01.x += __shfl_xor(a01.x, 32);
    a01.y += __shfl_xor(a01.y, 32);
    a23.x += __shfl_xor(a23.x, 32);
    a23.y += __shfl_xor(a23.y, 32);

    if (pair == 0) {
        float di = dinv[node];
        float r0 = a01.x * di + b[c];
        float r1 = a01.y * di + b[c + 1];
        float r2 = a23.x * di + b[c + 2];
        float r3 = a23.y * di + b[c + 3];
        uint2 o;
        o.x = (uint)f2bf(r0) | ((uint)f2bf(r1) << 16);
        o.y = (uint)f2bf(r2) | ((uint)f2bf(r3) << 16);
        *(uint2*)(AGG + (size_t)node * 128 + c) = o;
    }
}

// ---------------- BN stats: per-channel sum / sumsq (bf16 in) ----------------
__global__ __launch_bounds__(128) void k_bn_stats(const ushort_t* __restrict__ AGG,
                                                  float* __restrict__ stats) {
    int c = threadIdx.x;
    float s = 0.f, q = 0.f;
    for (int i = blockIdx.x; i < N_NODES; i += gridDim.x) {
        float v = bf2f(AGG[(size_t)i * 128 + c]);
        s += v;
        q += v * v;
    }
    atomicAdd(&stats[c], s);
    atomicAdd(&stats[128 + c], q);
}

// ---------------- BN apply (finalize fused) + ReLU (+ bf16 residual), bf16 out ----------------
__global__ __launch_bounds__(256) void k_bn_apply(const ushort_t* __restrict__ AGG,
                                                  const float* __restrict__ stats,
                                                  const float* __restrict__ gamma,
                                                  const float* __restrict__ beta,
                                                  const ushort_t* __restrict__ RES,  // may be null
                                                  ushort_t* __restrict__ OUT) {
    int tid = blockIdx.x * 256 + threadIdx.x;
    if (tid >= N_NODES * 32) return;
    int i = tid >> 5;
    int c = (tid & 31) * 4;

    const float invN = 1.0f / (float)N_NODES;
    float4 sm = *(const float4*)&stats[c];
    float4 sq = *(const float4*)&stats[128 + c];
    float4 gm = *(const float4*)&gamma[c];
    float4 bt = *(const float4*)&beta[c];
    float mu0 = sm.x * invN, mu1 = sm.y * invN, mu2 = sm.z * invN, mu3 = sm.w * invN;
    float sc0 = gm.x * rsqrtf(sq.x * invN - mu0 * mu0 + BN_EPS);
    float sc1 = gm.y * rsqrtf(sq.y * invN - mu1 * mu1 + BN_EPS);
    float sc2 = gm.z * rsqrtf(sq.z * invN - mu2 * mu2 + BN_EPS);
    float sc3 = gm.w * rsqrtf(sq.w * invN - mu3 * mu3 + BN_EPS);
    float sh0 = bt.x - mu0 * sc0, sh1 = bt.y - mu1 * sc1;
    float sh2 = bt.z - mu2 * sc2, sh3 = bt.w - mu3 * sc3;

    uint2 av = *(const uint2*)&AGG[(size_t)i * 128 + c];
    float y0 = bf2f((ushort_t)(av.x & 0xffff)) * sc0 + sh0;
    float y1 = bf2f((ushort_t)(av.x >> 16))    * sc1 + sh1;
    float y2 = bf2f((ushort_t)(av.y & 0xffff)) * sc2 + sh2;
    float y3 = bf2f((ushort_t)(av.y >> 16))    * sc3 + sh3;
    if (RES) {
        ushort4 rv = *(const ushort4*)&RES[(size_t)i * 128 + c];
        y0 += bf2f(rv.x); y1 += bf2f(rv.y); y2 += bf2f(rv.z); y3 += bf2f(rv.w);
    }
    ushort4 o;
    o.x = f2bf(fmaxf(y0, 0.f)); o.y = f2bf(fmaxf(y1, 0.f));
    o.z = f2bf(fmaxf(y2, 0.f)); o.w = f2bf(fmaxf(y3, 0.f));
    *(ushort4*)&OUT[(size_t)i * 128 + c] = o;
}

// ---------------- layer-3 fused BN apply + ReLU + residual + pool ----------------
// Never materializes out3: block = 128 threads (thread = channel), 100 nodes/chunk,
// segmented pool over sorted batch ids with atomic flush at boundaries.
#define POOL_CHUNK 100
__global__ __launch_bounds__(128) void k_bn_pool(const ushort_t* __restrict__ AGG,
                                                 const float* __restrict__ stats,
                                                 const float* __restrict__ gamma,
                                                 const float* __restrict__ beta,
                                                 const ushort_t* __restrict__ RES,
                                                 const int* __restrict__ batch,
                                                 float* __restrict__ psum,
                                                 uint* __restrict__ pmax,
                                                 float* __restrict__ pcnt) {
    int t = threadIdx.x;                        // channel
    const float invN = 1.0f / (float)N_NODES;
    float mu = stats[t] * invN;
    float sc = gamma[t] * rsqrtf(stats[128 + t] * invN - mu * mu + BN_EPS);
    float sh = beta[t] - mu * sc;

    int i0 = blockIdx.x * POOL_CHUNK;
    int i1 = min(i0 + POOL_CHUNK, N_NODES);
    if (i0 >= i1) return;

    int cur = batch[i0];
    float s = 0.f, m = 0.f, cntf = 0.f;
    for (int i = i0; i < i1; ++i) {
        int b = batch[i];
        float v = bf2f(AGG[(size_t)i * 128 + t]) * sc + sh + bf2f(RES[(size_t)i * 128 + t]);
        v = fmaxf(v, 0.f);
        if (b != cur) {
            atomicAdd(&psum[cur * 128 + t], s);
            atomicMax(&pmax[cur * 128 + t], __float_as_uint(m));
            if (t == 0) atomicAdd(&pcnt[cur], cntf);
            s = 0.f; m = 0.f; cntf = 0.f;
            cur = b;
        }
        s += v;
        m = fmaxf(m, v);   // post-ReLU >= 0: uint atomicMax == float max, init 0
        cntf += 1.f;
    }
    atomicAdd(&psum[cur * 128 + t], s);
    atomicMax(&pmax[cur * 128 + t], __float_as_uint(m));
    if (t == 0) atomicAdd(&pcnt[cur], cntf);
}

// ---------------- head ----------------
__global__ __launch_bounds__(64) void k_head(const float* __restrict__ psum,
                                             const uint* __restrict__ pmax,
                                             const float* __restrict__ pcnt,
                                             const float* __restrict__ Wh,
                                             const float* __restrict__ bh,
                                             float* __restrict__ out) {
    int g = blockIdx.x;
    int o = threadIdx.x;
    float cnt = pcnt[g];
    float inv = 1.0f / fmaxf(cnt, 1.0f);
    float acc = bh[o];
    for (int c = 0; c < 128; ++c) {
        float s = psum[g * 128 + c];
        float m = __uint_as_float(pmax[g * 128 + c]);
        acc += (s * inv) * Wh[c * 64 + o];
        acc += s * Wh[(128 + c) * 64 + o];
        acc += m * Wh[(256 + c) * 64 + o];
    }
    out[g * 64 + o] = acc;
}

// ---------------- host orchestration ----------------
extern "C" void kernel_launch(void* const* d_in, const int* in_sizes, int n_in,
                              void* d_out, int out_size, void* d_ws, size_t ws_size,
                              hipStream_t stream) {
    const float* x     = (const float*)d_in[0];
    const int*   ei    = (const int*)d_in[1];
    const int*   batch = (const int*)d_in[2];
    const float* W1 = (const float*)d_in[3];
    const float* b1 = (const float*)d_in[4];
    const float* g1 = (const float*)d_in[5];
    const float* be1= (const float*)d_in[6];
    const float* W2 = (const float*)d_in[7];
    const float* b2 = (const float*)d_in[8];
    const float* g2 = (const float*)d_in[9];
    const float* be2= (const float*)d_in[10];
    const float* W3 = (const float*)d_in[11];
    const float* b3 = (const float*)d_in[12];
    const float* g3 = (const float*)d_in[13];
    const float* be3= (const float*)d_in[14];
    const float* Wh = (const float*)d_in[15];
    const float* bh = (const float*)d_in[16];

    const int* src = ei;
    const int* dst = ei + N_EDGES;

    char* ws = (char*)d_ws;
    size_t off = 0;

    // ---- zero-initialized contiguous region (single memset) ----
    char* zero_base = ws;
    int*   cnt     = (int*)(ws + off);      off += 400384;                       // N_NODES*4 padded
    float* stats   = (float*)(ws + off);    off += 3 * 512 * 4;                  // 3 layers x 512 floats
    float* psum    = (float*)(ws + off);    off += (size_t)N_GRAPHS * CH * 4;
    uint*  pmax    = (uint*)(ws + off);     off += (size_t)N_GRAPHS * CH * 4;
    float* pcnt    = (float*)(ws + off);    off += 4096;
    size_t zero_bytes = off;

    // ---- uninitialized scratch ----
    float* dinv    = (float*)(ws + off);    off += 512 * 1024;
    ushort_t* XBA  = (ushort_t*)(ws + off); off += (size_t)N_PAD * CH * 2;
    ushort_t* XBB  = (ushort_t*)(ws + off); off += (size_t)N_PAD * CH * 2;
    ushort_t* H    = (ushort_t*)(ws + off); off += (size_t)N_PAD * CH * 2;
    ushort_t* AGG  = (ushort_t*)(ws + off); off += (size_t)N_PAD * CH * 2;
    ushort_t* Wt   = (ushort_t*)(ws + off); off += 3 * 16384 * 2;
    int*   lofs    = (int*)(ws + off);      off += 512 * 1024;
    int*   offs    = (int*)(ws + off);      off += 512 * 1024;      // N+1 ints
    int*   bsum    = (int*)(ws + off);      off += 4096;
    int*   rank    = (int*)(ws + off);      off += (size_t)N_EDGES * 4;
    int*   csr_src = (int*)(ws + off);      off += (size_t)N_EDGES * 4;

    const int SCAN_BLOCKS = (N_NODES + 511) / 512;   // 196

    hipMemsetAsync(zero_base, 0, zero_bytes, stream);

    // weight transpose + x cast, then degree/rank (separate dispatches — R8's
    // mega-fusion serialized the atomic partition behind the cast; keep split)
    const int cast_blocks = (N_NODES * 32 + 255) / 256;
    k_precast<<<PREP_BLOCKS + cast_blocks, 256, 0, stream>>>(W1, W2, W3, Wt, x, XBA);
    k_deg<<<(N_EDGES + 255) / 256, 256, 0, stream>>>(dst, cnt, rank);

    // scan(+dinv) / CSR fill
    k_scan1<<<SCAN_BLOCKS, 512, 0, stream>>>(cnt, lofs, bsum);
    k_scan2<<<1, 256, 0, stream>>>(bsum, SCAN_BLOCKS);
    k_scan3<<<(N_NODES + 255) / 256, 256, 0, stream>>>(lofs, bsum, cnt, offs, dinv);
    k_fill<<<(N_EDGES + 255) / 256, 256, 0, stream>>>(src, dst, offs, rank, csr_src);

    const int gemm_grid   = (N_NODES + 127) / 128;   // 782
    const int gather_grid = (N_NODES + 3) / 4;
    const int apply_grid  = (N_NODES * 32 + 255) / 256;
    const int pool_grid   = (N_NODES + POOL_CHUNK - 1) / POOL_CHUNK;

    struct Layer { const ushort_t* in; ushort_t* out; const ushort_t* Wt; const float* b;
                   const float* gm; const float* bt; const ushort_t* res; };
    Layer layers[3] = {
        { XBA, XBB, Wt,             b1, g1, be1, nullptr },
        { XBB, XBA, Wt + 16384,     b2, g2, be2, XBB     },
        { XBA, XBB, Wt + 2 * 16384, b3, g3, be3, XBA     },
    };

    for (int l = 0; l < 3; ++l) {
        const Layer& L = layers[l];
        float* st = stats + l * 512;
        k_gemm<<<gemm_grid, 256, 0, stream>>>(L.in, L.Wt, dinv, H);
        k_gather<<<gather_grid, 256, 0, stream>>>(csr_src, offs, dinv, H, L.b, AGG);
        k_bn_stats<<<1024, 128, 0, stream>>>(AGG, st);
        if (l < 2) {
            k_bn_apply<<<apply_grid, 256, 0, stream>>>(AGG, st, L.gm, L.bt, L.res, L.out);
        } else {
            // fused BN+ReLU+residual+pool — out3 never materialized
            k_bn_pool<<<pool_grid, 128, 0, stream>>>(AGG, st, L.gm, L.bt, L.res,
                                                     batch, psum, pmax, pcnt);
        }
    }

    k_head<<<N_GRAPHS, 64, 0, stream>>>(psum, pmax, pcnt, Wh, bh, (float*)d_out);
}